// Round 4
// baseline (268.567 us; speedup 1.0000x reference)
//
#include <hip/hip_runtime.h>
#include <hip/hip_bf16.h>

// Problem constants: B=2, C=128, T=512, F=512, H=8, d=64
#define CC 128
#define TT 512
#define FF 512
#define CS (TT * FF)

typedef __attribute__((ext_vector_type(8))) short short8;
typedef __attribute__((ext_vector_type(4))) float f32x4;
typedef __attribute__((ext_vector_type(4))) unsigned short u16x4;

__device__ __forceinline__ unsigned short f2b(float f) {
    union { float f; unsigned u; } a; a.f = f;
    unsigned r = a.u + 0x7fffu + ((a.u >> 16) & 1u);   // RNE to bf16
    return (unsigned short)(r >> 16);
}

// ===========================================================================
// NEW PATH
// ===========================================================================

// ---------------------------------------------------------------------------
// Kernel T: fused transpose-to-bf16 + mean partials.
// Block = (b, h, tc): reads x[b, c' 0..127, t0..t0+15, h*64..h*64+63] (512 KB),
// writes xt[b][h][t*64+f'][c'] bf16 (c' contiguous) + psum[bh][tc][c'][f'] f32.
// grid = 2*8*32 = 512 blocks, 512 threads.
// ---------------------------------------------------------------------------
__global__ __launch_bounds__(512) void tmean_kernel(const float* __restrict__ x,
                                                    unsigned short* __restrict__ xt,
                                                    float* __restrict__ psum) {
    int bid = blockIdx.x;
    int b = bid >> 8, h = (bid >> 5) & 7, tc = bid & 31;
    int t0 = tc * 16;
    __shared__ unsigned short ls[64][132];   // [f'][c'] bf16, +4 pad
    int tid = threadIdx.x;
    int f4 = tid & 15;        // float4 slot along f' (16 x 4 = 64)
    int cg = tid >> 4;        // 0..31 -> c'0 = cg*4
    int c0 = cg * 4;
    int dw = tid & 31;        // write-out: u16x4 slot along c' (32 x 4 = 128)
    int colr = tid >> 5;      // write-out: 0..15

    f32x4 macc[4];
    #pragma unroll
    for (int i = 0; i < 4; ++i) macc[i] = (f32x4){0.f, 0.f, 0.f, 0.f};

    unsigned short* xto = xt + (size_t)(b * 8 + h) * 32768 * 128;

    for (int trel = 0; trel < 16; ++trel) {
        int t = t0 + trel;
        f32x4 v[4];
        #pragma unroll
        for (int i = 0; i < 4; ++i) {
            v[i] = *(const f32x4*)(x + ((size_t)(b * CC + c0 + i) * TT + t) * FF
                                     + h * 64 + f4 * 4);
            macc[i] += v[i];
        }
        #pragma unroll
        for (int j = 0; j < 4; ++j) {
            u16x4 p = { f2b(v[0][j]), f2b(v[1][j]), f2b(v[2][j]), f2b(v[3][j]) };
            *(u16x4*)&ls[f4 * 4 + j][c0] = p;   // transpose into LDS
        }
        __syncthreads();
        #pragma unroll
        for (int i2 = 0; i2 < 4; ++i2) {
            int fp = colr + 16 * i2;   // f' 0..63
            u16x4 u = *(const u16x4*)&ls[fp][dw * 4];
            *(u16x4*)(xto + ((size_t)(t * 64 + fp) * 128) + dw * 4) = u;
        }
        __syncthreads();
    }
    float* pso = psum + ((size_t)(b * 8 + h) * 32 + tc) * 8192;
    #pragma unroll
    for (int i = 0; i < 4; ++i)
        *(f32x4*)(pso + (c0 + i) * 64 + f4 * 4) = macc[i];
}

// ---------------------------------------------------------------------------
// Kernel R: xm[b,c,f] = (1/512) * sum_tc psum[bh][tc][c][f'].  grid 512x256.
// ---------------------------------------------------------------------------
__global__ void xmred_kernel(const float* __restrict__ psum, float* __restrict__ xm) {
    int idx = blockIdx.x * 256 + threadIdx.x;   // 0..131071
    int b = idx >> 16, rem = idx & 65535;
    int c = rem >> 9, f = rem & 511;
    int h = f >> 6, fp = f & 63;
    const float* p = psum + (size_t)(b * 8 + h) * 32 * 8192 + c * 64 + fp;
    float s = 0.f;
    #pragma unroll
    for (int tc = 0; tc < 32; ++tc) s += p[tc * 8192];
    xm[idx] = s * (1.0f / 512.0f);
}

// ---------------------------------------------------------------------------
// Kernel C2: out[b,c,t,f] = sum_c' w[b,h(f),c,c'] * x[b,c',t,f], via xt.
// Per (b,h): Out(32768 cols x 128 c) = Xt(32768 x 128) @ W^T(128 x 128).
// MFMA roles: A = xt fragment (rows = memory cols), B = W^T -> D rows are
// 4 CONSECUTIVE memory cols per lane => float4 stores.
// grid = (64, 16), block = 256 (4 waves), 4 tiles/wave of 32 cols.
// ---------------------------------------------------------------------------
__global__ __launch_bounds__(256, 4) void wv2_kernel(const unsigned short* __restrict__ xt,
                                                     const float* __restrict__ wmat,
                                                     float* __restrict__ out) {
    int bh = blockIdx.y;
    int b = bh >> 3, h = bh & 7;
    __shared__ unsigned short Wl[128 * 128];   // 32 KB, swizzled bf16

    // stage W: b128 writes, slot = j ^ (c&7) uniform -> conflict-free
    {
        int tid = threadIdx.x;
        int c = tid & 127, half = tid >> 7;
        const float* wp = wmat + ((size_t)bh * 128 + c) * 128 + half * 64;
        unsigned swz = (unsigned)((c & 7) << 4);
        char* base = (char*)Wl + c * 256;
        #pragma unroll
        for (int j = 0; j < 8; ++j) {
            f32x4 v0 = *(const f32x4*)(wp + j * 8);
            f32x4 v1 = *(const f32x4*)(wp + j * 8 + 4);
            short8 pk;
            pk[0] = (short)f2b(v0[0]); pk[1] = (short)f2b(v0[1]);
            pk[2] = (short)f2b(v0[2]); pk[3] = (short)f2b(v0[3]);
            pk[4] = (short)f2b(v1[0]); pk[5] = (short)f2b(v1[1]);
            pk[6] = (short)f2b(v1[2]); pk[7] = (short)f2b(v1[3]);
            *(short8*)(base + (((unsigned)(half * 128 + j * 16)) ^ swz)) = pk;
        }
    }
    __syncthreads();

    int ln = threadIdx.x & 63, wq = threadIdx.x >> 6;
    int lan15 = ln & 15;     // A: memory-col within 16; B: c within 16; D: c
    int kg = ln >> 4;        // k-group 0..3
    const unsigned short* xth = xt + (size_t)bh * 32768 * 128;
    float* ob = out + (size_t)b * CC * CS;

    for (int it = 0; it < 4; ++it) {
        int ti = blockIdx.x * 4 + wq + it * 256;   // 0..1023
        int col0 = ti * 32;
        int t = col0 >> 6;
        int f0 = (h << 6) + (col0 & 63);

        // A fragments: 8 x b128 loads (8 consecutive c' each)
        const unsigned short* xa = xth + ((size_t)(col0 + lan15) << 7) + kg * 8;
        short8 af[2][4];
        #pragma unroll
        for (int nt = 0; nt < 2; ++nt)
            #pragma unroll
            for (int ks = 0; ks < 4; ++ks)
                af[nt][ks] = *(const short8*)(xa + (nt * 16 << 7) + ks * 32);

        float* oq = ob + (size_t)t * FF + f0 + kg * 4;
        #pragma unroll
        for (int m = 0; m < 8; ++m) {
            f32x4 a0 = (f32x4){0.f, 0.f, 0.f, 0.f};
            f32x4 a1 = (f32x4){0.f, 0.f, 0.f, 0.f};
            int r = m * 16 + lan15;
            const char* bp = (const char*)Wl + r * 256;
            unsigned sw = (unsigned)((r & 7) << 4);
            #pragma unroll
            for (int ks = 0; ks < 4; ++ks) {
                short8 bw = *(const short8*)(bp + (((unsigned)(ks * 64 + kg * 16)) ^ sw));
                a0 = __builtin_amdgcn_mfma_f32_16x16x32_bf16(af[0][ks], bw, a0, 0, 0, 0);
                a1 = __builtin_amdgcn_mfma_f32_16x16x32_bf16(af[1][ks], bw, a1, 0, 0, 0);
            }
            float* op = oq + (size_t)r * CS;
            *(f32x4*)op = a0;          // cols f0 + kg*4 + 0..3
            *(f32x4*)(op + 16) = a1;   // nt=1 half
        }
    }
}

// ===========================================================================
// SHARED (both paths): qk + softmax
// ===========================================================================
__global__ void qk_kernel(const float* __restrict__ xm, const float* __restrict__ Wq,
                          const float* __restrict__ bq, const float* __restrict__ Wk,
                          float* __restrict__ qo, float* __restrict__ ko) {
    __shared__ float xs[32][65];
    __shared__ float wqs[32][65];
    __shared__ float wks[32][65];
    int ft = blockIdx.x, rt = blockIdx.y;
    int t = threadIdx.x;
    int tx = t & 15, ty = t >> 4;
    float qa[2][2] = {{0.f,0.f},{0.f,0.f}}, ka[2][2] = {{0.f,0.f},{0.f,0.f}};
    for (int kc = 0; kc < 512; kc += 64) {
        __syncthreads();
        for (int i = t; i < 2048; i += 256) {
            int r = i >> 6, cc2 = i & 63;
            xs[r][cc2]  = xm[(rt * 32 + r) * 512 + kc + cc2];
            wqs[r][cc2] = Wq[(ft * 32 + r) * 512 + kc + cc2];
            wks[r][cc2] = Wk[(ft * 32 + r) * 512 + kc + cc2];
        }
        __syncthreads();
        #pragma unroll 8
        for (int kk = 0; kk < 64; ++kk) {
            float x0 = xs[ty*2][kk],  x1 = xs[ty*2+1][kk];
            float a0 = wqs[tx*2][kk], a1 = wqs[tx*2+1][kk];
            float b0 = wks[tx*2][kk], b1 = wks[tx*2+1][kk];
            qa[0][0] += x0*a0; qa[0][1] += x0*a1;
            qa[1][0] += x1*a0; qa[1][1] += x1*a1;
            ka[0][0] += x0*b0; ka[0][1] += x0*b1;
            ka[1][0] += x1*b0; ka[1][1] += x1*b1;
        }
    }
    #pragma unroll
    for (int i = 0; i < 2; ++i) {
        int r = rt * 32 + ty * 2 + i;
        #pragma unroll
        for (int j = 0; j < 2; ++j) {
            int f = ft * 32 + tx * 2 + j;
            qo[r * 512 + f] = qa[i][j] + bq[f];
            ko[r * 512 + f] = ka[i][j];
        }
    }
}

__global__ void attn_w_kernel(const float* __restrict__ q, const float* __restrict__ k,
                              float* __restrict__ w) {
    int idx = blockIdx.x;
    int bh = idx >> 7, c = idx & 127;
    int b = bh >> 3, h = bh & 7;
    int f0 = h * 64;
    __shared__ float qv[64];
    __shared__ float wmax[2];
    __shared__ float wsum[2];
    int t = threadIdx.x;     // = c'
    if (t < 64) qv[t] = q[((b * CC + c) * FF) + f0 + t];
    __syncthreads();
    const float* kp = k + ((size_t)(b * CC + t) * FF) + f0;
    float acc = 0.f;
    #pragma unroll
    for (int j = 0; j < 64; j += 4) {
        float4 kv = *(const float4*)(kp + j);
        acc += qv[j] * kv.x + qv[j+1] * kv.y + qv[j+2] * kv.z + qv[j+3] * kv.w;
    }
    float logit = acc * 0.125f;   // d^{-1/2}, d = 64
    float m = logit;
    #pragma unroll
    for (int o = 32; o >= 1; o >>= 1) m = fmaxf(m, __shfl_xor(m, o));
    if ((t & 63) == 0) wmax[t >> 6] = m;
    __syncthreads();
    m = fmaxf(wmax[0], wmax[1]);
    float e = expf(logit - m);
    float s = e;
    #pragma unroll
    for (int o = 32; o >= 1; o >>= 1) s += __shfl_xor(s, o);
    if ((t & 63) == 0) wsum[t >> 6] = s;
    __syncthreads();
    s = wsum[0] + wsum[1];
    w[((size_t)bh * 128 + c) * 128 + t] = e / s;
}

// ===========================================================================
// FALLBACK PATH (if ws too small): proven R1 kernels
// ===========================================================================
__global__ __launch_bounds__(1024) void mean_kernel(const float* __restrict__ x,
                                                    float* __restrict__ xm) {
    int bc = blockIdx.x;
    int q4  = threadIdx.x & 127;
    int par = threadIdx.x >> 7;
    const float4* xp = (const float4*)(x + (size_t)bc * (TT * FF));
    float4 s0 = make_float4(0.f,0.f,0.f,0.f), s1 = make_float4(0.f,0.f,0.f,0.f);
    float4 s2 = make_float4(0.f,0.f,0.f,0.f), s3 = make_float4(0.f,0.f,0.f,0.f);
    #pragma unroll 4
    for (int k = 0; k < 64; k += 4) {
        float4 a = xp[(par + 8 * k) * 128 + q4];
        float4 b = xp[(par + 8 * (k + 1)) * 128 + q4];
        float4 c = xp[(par + 8 * (k + 2)) * 128 + q4];
        float4 d = xp[(par + 8 * (k + 3)) * 128 + q4];
        s0.x += a.x; s0.y += a.y; s0.z += a.z; s0.w += a.w;
        s1.x += b.x; s1.y += b.y; s1.z += b.z; s1.w += b.w;
        s2.x += c.x; s2.y += c.y; s2.z += c.z; s2.w += c.w;
        s3.x += d.x; s3.y += d.y; s3.z += d.z; s3.w += d.w;
    }
    s0.x += s1.x + s2.x + s3.x; s0.y += s1.y + s2.y + s3.y;
    s0.z += s1.z + s2.z + s3.z; s0.w += s1.w + s2.w + s3.w;
    __shared__ float4 part[1024];
    part[threadIdx.x] = s0;
    __syncthreads();
    if (par == 0) {
        const float inv = 1.0f / (float)TT;
        float4 acc = make_float4(0.f,0.f,0.f,0.f);
        #pragma unroll
        for (int j = 0; j < 8; ++j) {
            float4 v = part[q4 + 128 * j];
            acc.x += v.x; acc.y += v.y; acc.z += v.z; acc.w += v.w;
        }
        acc.x *= inv; acc.y *= inv; acc.z *= inv; acc.w *= inv;
        ((float4*)xm)[bc * 128 + q4] = acc;
    }
}

__global__ __launch_bounds__(256, 2) void wv_kernel(const float* __restrict__ x,
                                                    const float* __restrict__ wmat,
                                                    float* __restrict__ out) {
    int bh = blockIdx.y;
    int b = bh >> 3, h = bh & 7;
    __shared__ unsigned short Wl[128 * 128];
    {
        int t = threadIdx.x;
        int c = t >> 1;
        int half = (t & 1) << 6;
        const float* wp = wmat + ((size_t)bh * 128 + c) * 128 + half;
        unsigned swz = (unsigned)((c & 7) << 4);
        char* base = (char*)Wl + c * 256;
        #pragma unroll
        for (int i = 0; i < 64; i += 4) {
            float4 v = *(const float4*)(wp + i);
            unsigned p0 = (unsigned)f2b(v.x) | ((unsigned)f2b(v.y) << 16);
            unsigned p1 = (unsigned)f2b(v.z) | ((unsigned)f2b(v.w) << 16);
            unsigned e2 = (unsigned)((half + i) << 1);
            *(unsigned*)(base + ((e2     ) ^ swz)) = p0;
            *(unsigned*)(base + ((e2 + 4u) ^ swz)) = p1;
        }
    }
    __syncthreads();
    int ln  = threadIdx.x & 63;
    int wv_ = threadIdx.x >> 6;
    int nco = ln & 15;
    int kg  = ln >> 4;
    int arow = ln & 15;
    unsigned aswz = (unsigned)((arow & 7) << 4);
    const float* xb = x + (size_t)b * CC * CS;
    float* ob = out + (size_t)b * CC * CS;
    for (int it = 0; it < 8; ++it) {
        int ti = blockIdx.x * 4 + wv_ + it * 128;
        int col0 = ti << 5;
        int t = col0 >> 6;
        int fbase = (h << 6) + (col0 & 63);
        const float* xc = xb + (size_t)t * FF + fbase + nco + (size_t)(kg * 8) * CS;
        f32x4 acc[8][2];
        #pragma unroll
        for (int m = 0; m < 8; ++m) {
            acc[m][0] = (f32x4){0.f, 0.f, 0.f, 0.f};
            acc[m][1] = (f32x4){0.f, 0.f, 0.f, 0.f};
        }
        #pragma unroll
        for (int ks = 0; ks < 4; ++ks) {
            const float* p0 = xc + (size_t)(ks * 32) * CS;
            short8 bf[2];
            #pragma unroll
            for (int nt = 0; nt < 2; ++nt) {
                const float* p = p0 + nt * 16;
                short8 bb;
                #pragma unroll
                for (int j = 0; j < 8; ++j) bb[j] = (short)f2b(p[(size_t)j * CS]);
                bf[nt] = bb;
            }
            #pragma unroll
            for (int m = 0; m < 8; ++m) {
                unsigned abyte = (unsigned)((m * 16 + arow) * 256)
                               + (((unsigned)((ks * 4 + kg) << 4)) ^ aswz);
                short8 af = *(const short8*)((const char*)Wl + abyte);
                acc[m][0] = __builtin_amdgcn_mfma_f32_16x16x32_bf16(af, bf[0], acc[m][0], 0, 0, 0);
                acc[m][1] = __builtin_amdgcn_mfma_f32_16x16x32_bf16(af, bf[1], acc[m][1], 0, 0, 0);
            }
        }
        float* o0 = ob + (size_t)t * FF + fbase + nco;
        #pragma unroll
        for (int m = 0; m < 8; ++m) {
            int crow = m * 16 + kg * 4;
            float* op0 = o0 + (size_t)crow * CS;
            #pragma unroll
            for (int j = 0; j < 4; ++j) {
                op0[(size_t)j * CS]      = acc[m][0][j];
                op0[(size_t)j * CS + 16] = acc[m][1][j];
            }
        }
    }
}

// ---------------------------------------------------------------------------
extern "C" void kernel_launch(void* const* d_in, const int* in_sizes, int n_in,
                              void* d_out, int out_size, void* d_ws, size_t ws_size,
                              hipStream_t stream) {
    (void)in_sizes; (void)n_in; (void)out_size;
    const float* x  = (const float*)d_in[0];
    const float* Wq = (const float*)d_in[1];
    const float* bq = (const float*)d_in[2];
    const float* Wk = (const float*)d_in[3];
    float* out = (float*)d_out;

    const size_t REQ = 134217728ull + 16777216ull + 4ull * 524288ull; // xt+psum+xm/q/k(3*512K)... see below
    // exact: xt 134217728 + psum 16777216 + xm 524288 + q 524288 + k 524288 + w 1048576
    const size_t NEED = 134217728ull + 16777216ull + 524288ull * 3ull + 1048576ull;
    (void)REQ;

    if (ws_size >= NEED) {
        char* wsb = (char*)d_ws;
        unsigned short* xt = (unsigned short*)wsb;
        float* psum = (float*)(wsb + 134217728ull);
        float* xm   = psum + 4194304;
        float* q    = xm + 131072;
        float* k    = q + 131072;
        float* w    = k + 131072;

        hipLaunchKernelGGL(tmean_kernel,  dim3(512),    dim3(512), 0, stream, x, xt, psum);
        hipLaunchKernelGGL(xmred_kernel,  dim3(512),    dim3(256), 0, stream, psum, xm);
        hipLaunchKernelGGL(qk_kernel,     dim3(16, 8),  dim3(256), 0, stream, xm, Wq, bq, Wk, q, k);
        hipLaunchKernelGGL(attn_w_kernel, dim3(2048),   dim3(128), 0, stream, q, k, w);
        hipLaunchKernelGGL(wv2_kernel,    dim3(64, 16), dim3(256), 0, stream, xt, w, out);
    } else {
        float* ws = (float*)d_ws;
        float* xm = ws;
        float* q  = ws + 131072;
        float* k  = ws + 262144;
        float* w  = ws + 393216;
        hipLaunchKernelGGL(mean_kernel,   dim3(256),    dim3(1024), 0, stream, x, xm);
        hipLaunchKernelGGL(qk_kernel,     dim3(16, 8),  dim3(256),  0, stream, xm, Wq, bq, Wk, q, k);
        hipLaunchKernelGGL(attn_w_kernel, dim3(2048),   dim3(128),  0, stream, q, k, w);
        hipLaunchKernelGGL(wv_kernel,     dim3(32, 16), dim3(256),  0, stream, x, w, out);
    }
}

// Round 5
// 226.676 us; speedup vs baseline: 1.1848x; 1.1848x over previous
//
#include <hip/hip_runtime.h>
#include <hip/hip_bf16.h>

// Problem constants: B=2, C=128, T=512, F=512, H=8, d=64
#define CC 128
#define TT 512
#define FF 512
#define CS (TT * FF)

typedef __attribute__((ext_vector_type(8))) short short8;
typedef __attribute__((ext_vector_type(4))) float f32x4;

__device__ __forceinline__ unsigned short f2b(float f) {
    union { float f; unsigned u; } a; a.f = f;
    unsigned r = a.u + 0x7fffu + ((a.u >> 16) & 1u);   // RNE to bf16
    return (unsigned short)(r >> 16);
}

// ---------------------------------------------------------------------------
// Kernel A: xm[b,c,f] = mean_t x[b,c,t,f].  grid=256 (b*C+c), block=1024.
// (R3 version, ~60 us — unchanged for clean attribution.)
// ---------------------------------------------------------------------------
__global__ __launch_bounds__(1024) void mean_kernel(const float* __restrict__ x,
                                                    float* __restrict__ xm) {
    int bc = blockIdx.x;
    int q4  = threadIdx.x & 127;
    int par = threadIdx.x >> 7;
    const float4* xp = (const float4*)(x + (size_t)bc * (TT * FF));
    float4 s0 = make_float4(0.f,0.f,0.f,0.f), s1 = make_float4(0.f,0.f,0.f,0.f);
    float4 s2 = make_float4(0.f,0.f,0.f,0.f), s3 = make_float4(0.f,0.f,0.f,0.f);
    #pragma unroll 4
    for (int k = 0; k < 64; k += 4) {
        float4 a = xp[(par + 8 * k) * 128 + q4];
        float4 b = xp[(par + 8 * (k + 1)) * 128 + q4];
        float4 c = xp[(par + 8 * (k + 2)) * 128 + q4];
        float4 d = xp[(par + 8 * (k + 3)) * 128 + q4];
        s0.x += a.x; s0.y += a.y; s0.z += a.z; s0.w += a.w;
        s1.x += b.x; s1.y += b.y; s1.z += b.z; s1.w += b.w;
        s2.x += c.x; s2.y += c.y; s2.z += c.z; s2.w += c.w;
        s3.x += d.x; s3.y += d.y; s3.z += d.z; s3.w += d.w;
    }
    s0.x += s1.x + s2.x + s3.x; s0.y += s1.y + s2.y + s3.y;
    s0.z += s1.z + s2.z + s3.z; s0.w += s1.w + s2.w + s3.w;
    __shared__ float4 part[1024];
    part[threadIdx.x] = s0;
    __syncthreads();
    if (par == 0) {
        const float inv = 1.0f / (float)TT;
        float4 acc = make_float4(0.f,0.f,0.f,0.f);
        #pragma unroll
        for (int j = 0; j < 8; ++j) {
            float4 v = part[q4 + 128 * j];
            acc.x += v.x; acc.y += v.y; acc.z += v.z; acc.w += v.w;
        }
        acc.x *= inv; acc.y *= inv; acc.z *= inv; acc.w *= inv;
        ((float4*)xm)[bc * 128 + q4] = acc;
    }
}

// ---------------------------------------------------------------------------
// Kernel B1: q = xm @ Wq^T + bq ; k = xm @ Wk^T
// ---------------------------------------------------------------------------
__global__ void qk_kernel(const float* __restrict__ xm, const float* __restrict__ Wq,
                          const float* __restrict__ bq, const float* __restrict__ Wk,
                          float* __restrict__ qo, float* __restrict__ ko) {
    __shared__ float xs[32][65];
    __shared__ float wqs[32][65];
    __shared__ float wks[32][65];
    int ft = blockIdx.x, rt = blockIdx.y;
    int t = threadIdx.x;
    int tx = t & 15, ty = t >> 4;
    float qa[2][2] = {{0.f,0.f},{0.f,0.f}}, ka[2][2] = {{0.f,0.f},{0.f,0.f}};
    for (int kc = 0; kc < 512; kc += 64) {
        __syncthreads();
        for (int i = t; i < 2048; i += 256) {
            int r = i >> 6, cc2 = i & 63;
            xs[r][cc2]  = xm[(rt * 32 + r) * 512 + kc + cc2];
            wqs[r][cc2] = Wq[(ft * 32 + r) * 512 + kc + cc2];
            wks[r][cc2] = Wk[(ft * 32 + r) * 512 + kc + cc2];
        }
        __syncthreads();
        #pragma unroll 8
        for (int kk = 0; kk < 64; ++kk) {
            float x0 = xs[ty*2][kk],  x1 = xs[ty*2+1][kk];
            float a0 = wqs[tx*2][kk], a1 = wqs[tx*2+1][kk];
            float b0 = wks[tx*2][kk], b1 = wks[tx*2+1][kk];
            qa[0][0] += x0*a0; qa[0][1] += x0*a1;
            qa[1][0] += x1*a0; qa[1][1] += x1*a1;
            ka[0][0] += x0*b0; ka[0][1] += x0*b1;
            ka[1][0] += x1*b0; ka[1][1] += x1*b1;
        }
    }
    #pragma unroll
    for (int i = 0; i < 2; ++i) {
        int r = rt * 32 + ty * 2 + i;
        #pragma unroll
        for (int j = 0; j < 2; ++j) {
            int f = ft * 32 + tx * 2 + j;
            qo[r * 512 + f] = qa[i][j] + bq[f];
            ko[r * 512 + f] = ka[i][j];
        }
    }
}

// ---------------------------------------------------------------------------
// Kernel B2: logits + softmax -> w[bh][c][c'].
// ---------------------------------------------------------------------------
__global__ void attn_w_kernel(const float* __restrict__ q, const float* __restrict__ k,
                              float* __restrict__ w) {
    int idx = blockIdx.x;
    int bh = idx >> 7, c = idx & 127;
    int b = bh >> 3, h = bh & 7;
    int f0 = h * 64;
    __shared__ float qv[64];
    __shared__ float wmax[2];
    __shared__ float wsum[2];
    int t = threadIdx.x;     // = c'
    if (t < 64) qv[t] = q[((b * CC + c) * FF) + f0 + t];
    __syncthreads();
    const float* kp = k + ((size_t)(b * CC + t) * FF) + f0;
    float acc = 0.f;
    #pragma unroll
    for (int j = 0; j < 64; j += 4) {
        float4 kv = *(const float4*)(kp + j);
        acc += qv[j] * kv.x + qv[j+1] * kv.y + qv[j+2] * kv.z + qv[j+3] * kv.w;
    }
    float logit = acc * 0.125f;   // d^{-1/2}, d = 64
    float m = logit;
    #pragma unroll
    for (int o = 32; o >= 1; o >>= 1) m = fmaxf(m, __shfl_xor(m, o));
    if ((t & 63) == 0) wmax[t >> 6] = m;
    __syncthreads();
    m = fmaxf(wmax[0], wmax[1]);
    float e = expf(logit - m);
    float s = e;
    #pragma unroll
    for (int o = 32; o >= 1; o >>= 1) s += __shfl_xor(s, o);
    if ((t & 63) == 0) wsum[t >> 6] = s;
    __syncthreads();
    s = wsum[0] + wsum[1];
    w[((size_t)bh * 128 + c) * 128 + t] = e / s;
}

// ---------------------------------------------------------------------------
// Kernel C (wv3): out[b,c,col] = sum_c' W[bh][c][c'] * x[b,c',col]
// ROLE SWAP: MFMA A = x-fragment (A rows = output cols), B = W^T from LDS.
// => each lane's f32x4 acc = 4 CONSECUTIVE output cols -> b128 stores.
// Fine-grained interleave per ks-phase (R1's proven pipeline-friendly shape):
//   16 scalar x-loads -> convert -> 8 ds_read_b128 + 16 MFMA.
// grid = (64, 16=bh), block = 256 (4 waves), 4 tiles of 32 cols per wave.
// ---------------------------------------------------------------------------
__global__ __launch_bounds__(256, 2) void wv3_kernel(const float* __restrict__ x,
                                                     const float* __restrict__ wmat,
                                                     float* __restrict__ out) {
    int bh = blockIdx.y;
    int b = bh >> 3, h = bh & 7;
    __shared__ unsigned short Wl[128 * 128];   // 32 KB, swizzled bf16

    // stage W: b128 writes; row c, elem e -> byte c*256 + ((2e) ^ ((c&7)<<4))
    {
        int tid = threadIdx.x;
        int c = tid & 127, half = tid >> 7;
        const float* wp = wmat + ((size_t)bh * 128 + c) * 128 + half * 64;
        unsigned swz = (unsigned)((c & 7) << 4);
        char* base = (char*)Wl + c * 256;
        #pragma unroll
        for (int j = 0; j < 8; ++j) {
            f32x4 v0 = *(const f32x4*)(wp + j * 8);
            f32x4 v1 = *(const f32x4*)(wp + j * 8 + 4);
            short8 pk;
            pk[0] = (short)f2b(v0[0]); pk[1] = (short)f2b(v0[1]);
            pk[2] = (short)f2b(v0[2]); pk[3] = (short)f2b(v0[3]);
            pk[4] = (short)f2b(v1[0]); pk[5] = (short)f2b(v1[1]);
            pk[6] = (short)f2b(v1[2]); pk[7] = (short)f2b(v1[3]);
            *(short8*)(base + (((unsigned)(half * 128 + j * 16)) ^ swz)) = pk;
        }
    }
    __syncthreads();

    int ln  = threadIdx.x & 63;
    int wq  = threadIdx.x >> 6;
    int l15 = ln & 15;       // A row (col within 16-tile) / store c-row / B col
    int kg  = ln >> 4;       // k-group 0..3
    const float* xb = x + (size_t)b * CC * CS;
    float* ob = out + (size_t)b * CC * CS;

    for (int it = 0; it < 4; ++it) {
        int ti = blockIdx.x * 4 + wq + it * 256;    // 0..1023
        int col0 = ti << 5;
        size_t cbase = (size_t)(col0 >> 6) * FF + (h << 6) + (col0 & 63);
        const float* xl = xb + cbase + l15 + (size_t)(kg * 8) * CS;

        f32x4 acc[2][8];
        #pragma unroll
        for (int mt = 0; mt < 2; ++mt)
            #pragma unroll
            for (int ct = 0; ct < 8; ++ct)
                acc[mt][ct] = (f32x4){0.f, 0.f, 0.f, 0.f};

        #pragma unroll
        for (int ks = 0; ks < 4; ++ks) {
            // A-fragments: lane (l15, kg) needs x[c'=ks*32+kg*8+j][col0 + mt*16 + l15]
            const float* p = xl + (size_t)(ks * 32) * CS;
            float v[8], u[8];
            #pragma unroll
            for (int j = 0; j < 8; ++j) {
                v[j] = p[(size_t)j * CS];         // mt = 0
                u[j] = p[(size_t)j * CS + 16];    // mt = 1
            }
            short8 a0, a1;
            #pragma unroll
            for (int j = 0; j < 8; ++j) {
                a0[j] = (short)f2b(v[j]);
                a1[j] = (short)f2b(u[j]);
            }
            #pragma unroll
            for (int ct = 0; ct < 8; ++ct) {
                int r = ct * 16 + l15;            // B col = c
                const char* bp = (const char*)Wl + r * 256;
                unsigned sw2 = (unsigned)((r & 7) << 4);
                short8 wf = *(const short8*)(bp + (((unsigned)(ks * 64 + kg * 16)) ^ sw2));
                acc[0][ct] = __builtin_amdgcn_mfma_f32_16x16x32_bf16(a0, wf, acc[0][ct], 0, 0, 0);
                acc[1][ct] = __builtin_amdgcn_mfma_f32_16x16x32_bf16(a1, wf, acc[1][ct], 0, 0, 0);
            }
        }

        // stores: lane (l15, kg) holds out[c = ct*16+l15][col0 + mt*16 + kg*4 + 0..3]
        float* o0 = ob + cbase + kg * 4;
        #pragma unroll
        for (int ct = 0; ct < 8; ++ct) {
            float* op = o0 + (size_t)(ct * 16 + l15) * CS;
            *(f32x4*)op        = acc[0][ct];
            *(f32x4*)(op + 16) = acc[1][ct];
        }
    }
}

// ---------------------------------------------------------------------------
extern "C" void kernel_launch(void* const* d_in, const int* in_sizes, int n_in,
                              void* d_out, int out_size, void* d_ws, size_t ws_size,
                              hipStream_t stream) {
    (void)in_sizes; (void)n_in; (void)out_size; (void)ws_size;
    const float* x  = (const float*)d_in[0];
    const float* Wq = (const float*)d_in[1];
    const float* bq = (const float*)d_in[2];
    const float* Wk = (const float*)d_in[3];
    float* out = (float*)d_out;

    // workspace layout (floats): xm[131072] q[131072] k[131072] w[262144]
    float* ws = (float*)d_ws;
    float* xm = ws;
    float* q  = ws + 131072;
    float* k  = ws + 262144;
    float* w  = ws + 393216;

    hipLaunchKernelGGL(mean_kernel,   dim3(256),    dim3(1024), 0, stream, x, xm);
    hipLaunchKernelGGL(qk_kernel,     dim3(16, 8),  dim3(256),  0, stream, xm, Wq, bq, Wk, q, k);
    hipLaunchKernelGGL(attn_w_kernel, dim3(2048),   dim3(128),  0, stream, q, k, w);
    hipLaunchKernelGGL(wv3_kernel,    dim3(64, 16), dim3(256),  0, stream, x, w, out);
}